// Round 7
// baseline (162.726 us; speedup 1.0000x reference)
//
#include <hip/hip_runtime.h>

#define N 8192
#define D 128
#define CHUNK 1024
#define NCHUNK 8   // column chunks
#define TILE_IT 8  // 128-col tiles per chunk
// sqrt(10): dot of two scaled rows = cos_sim/T directly; e = __expf(acc)
#define PREP_SCALE 3.16227766017f

typedef unsigned short u16;
typedef __attribute__((ext_vector_type(8))) __bf16 bf16x8;
typedef __attribute__((ext_vector_type(4))) float f32x4;

__device__ __forceinline__ u16 f2bf(float x) {
  unsigned u = __float_as_uint(x);
  u += 0x7fff + ((u >> 16) & 1);  // RNE
  return (u16)(u >> 16);
}
__device__ __forceinline__ float bf2f(u16 h) {
  return __uint_as_float(((unsigned)h) << 16);
}
// XOR-swizzled LDS offset (u16 units): row r (0..127), 16B-chunk c (0..15).
// R2-measured: 0 bank conflicts with this layout.
__device__ __forceinline__ int swz(int r, int c) {
  return r * 128 + ((c ^ (r & 15)) << 3);
}

// ---- kernel 1: normalize+scale rows, ZERO bg rows, split hi/lo; zero accum -
__global__ __launch_bounds__(256) void cpe_prep(const float* __restrict__ feat,
                                                const int* __restrict__ labels,
                                                u16* __restrict__ fhi,
                                                u16* __restrict__ flo,
                                                float* __restrict__ accum,
                                                int* __restrict__ cnt) {
  if (blockIdx.x == 0) {
    if (threadIdx.x < 4) accum[threadIdx.x] = 0.0f;
    if (threadIdx.x < 64) cnt[threadIdx.x] = 0;
  }
  const int w = threadIdx.x >> 6, l = threadIdx.x & 63, q = l >> 4, m = l & 15;
  const int row = (int)blockIdx.x * 16 + w * 4 + q;  // 16 rows/block
  const int lab = labels[row];
  const float4 x0 = *(const float4*)&feat[row * D + m * 8];
  const float4 x1 = *(const float4*)&feat[row * D + m * 8 + 4];
  float s = x0.x * x0.x + x0.y * x0.y + x0.z * x0.z + x0.w * x0.w +
            x1.x * x1.x + x1.y * x1.y + x1.z * x1.z + x1.w * x1.w;
#pragma unroll
  for (int sh = 1; sh < 16; sh <<= 1) s += __shfl_xor(s, sh);
  float inv = PREP_SCALE / fmaxf(sqrtf(s), 1e-12f);
  if (lab < 0) inv = 0.0f;  // bg rows -> sim=0 -> e=1, subtracted exactly later
  const float a[8] = {x0.x * inv, x0.y * inv, x0.z * inv, x0.w * inv,
                      x1.x * inv, x1.y * inv, x1.z * inv, x1.w * inv};
  u16 h[8], lo[8];
#pragma unroll
  for (int k = 0; k < 8; ++k) {
    h[k] = f2bf(a[k]);
    lo[k] = f2bf(a[k] - bf2f(h[k]));
  }
  *(ushort4*)&fhi[row * D + m * 8] = make_ushort4(h[0], h[1], h[2], h[3]);
  *(ushort4*)&fhi[row * D + m * 8 + 4] = make_ushort4(h[4], h[5], h[6], h[7]);
  *(ushort4*)&flo[row * D + m * 8] = make_ushort4(lo[0], lo[1], lo[2], lo[3]);
  *(ushort4*)&flo[row * D + m * 8 + 4] = make_ushort4(lo[4], lo[5], lo[6], lo[7]);
}

// ---- kernel 2: R2 memory structure (grid (64,8), wave=32 rows, ds_write
// staging) + thin exact epilogue + fused row-fold. sim = Ah·(Bh+Bl).
__global__ __launch_bounds__(256, 2) void cpe_main(
    const u16* __restrict__ fhi, const u16* __restrict__ flo,
    const int* __restrict__ labels, float2* __restrict__ partials,
    float* __restrict__ eself, float* __restrict__ accum,
    int* __restrict__ cnt, float* __restrict__ out) {
  __shared__ __align__(16) u16 Bh[128 * 128];  // 32 KB, XOR-swizzled
  __shared__ __align__(16) u16 Bl[128 * 128];  // 32 KB
  __shared__ int Lab[CHUNK];                   // 4 KB
  __shared__ float red[2][2];
  __shared__ int lastflag;
  const int rt = blockIdx.x, cc = blockIdx.y;  // 64 row-tiles x 8 chunks
  const int tid = threadIdx.x;
  const int w = tid >> 6, l = tid & 63, q = l >> 4, m = l & 15;
  const int r0w = rt * 128 + w * 32;  // wave owns 32 rows (2 tr of 16)
  const int cbase0 = cc * CHUNK;

#pragma unroll
  for (int i = 0; i < 4; ++i) Lab[tid + i * 256] = labels[cbase0 + tid + i * 256];

  // A-hi fragments (32 VGPRs) + row labels, straight from L2
  bf16x8 Ah[2][4];
  int labi[2][4];
#pragma unroll
  for (int tr = 0; tr < 2; ++tr) {
    const int row = r0w + tr * 16 + m;
#pragma unroll
    for (int ks = 0; ks < 4; ++ks)
      Ah[tr][ks] = *(const bf16x8*)&fhi[row * D + ks * 32 + q * 8];
#pragma unroll
    for (int v = 0; v < 4; ++v) labi[tr][v] = labels[r0w + tr * 16 + q * 4 + v];
  }

  float ps[2][4], as_[2][4], es_reg[2], bgc = 0.f;
#pragma unroll
  for (int tr = 0; tr < 2; ++tr) {
    es_reg[tr] = 0.f;
#pragma unroll
    for (int v = 0; v < 4; ++v) { ps[tr][v] = 0.f; as_[tr][v] = 0.f; }
  }

  for (int it = 0; it < TILE_IT; ++it) {
    const int cbase = cbase0 + it * 128;
    __syncthreads();  // prior tile's LDS reads done (covers Lab for it=0)
#pragma unroll
    for (int i = 0; i < 8; ++i) {  // R2-style staging: vector load + ds_write
      const int idx = tid + i * 256;
      const int r = idx >> 4, c = idx & 15;
      *(uint4*)&Bh[swz(r, c)] = *(const uint4*)&fhi[(size_t)(cbase + r) * D + c * 8];
      *(uint4*)&Bl[swz(r, c)] = *(const uint4*)&flo[(size_t)(cbase + r) * D + c * 8];
    }
    __syncthreads();

    for (int ct = 0; ct < 8; ++ct) {
      const int jj = ct * 16 + m;
      const int jbase = cbase + ct * 16;
      const int labj = Lab[it * 128 + jj];
      f32x4 acc0 = {0.f, 0.f, 0.f, 0.f}, acc1 = {0.f, 0.f, 0.f, 0.f};
#pragma unroll
      for (int ks = 0; ks < 4; ++ks) {
        const int off = jj * 128 + ((ks * 4 + q) ^ m) * 8;  // swizzled
        const bf16x8 bh = *(const bf16x8*)&Bh[off];
        const bf16x8 bl = *(const bf16x8*)&Bl[off];
        acc0 = __builtin_amdgcn_mfma_f32_16x16x32_bf16(Ah[0][ks], bh, acc0, 0, 0, 0);
        acc1 = __builtin_amdgcn_mfma_f32_16x16x32_bf16(Ah[1][ks], bh, acc1, 0, 0, 0);
        acc0 = __builtin_amdgcn_mfma_f32_16x16x32_bf16(Ah[0][ks], bl, acc0, 0, 0, 0);
        acc1 = __builtin_amdgcn_mfma_f32_16x16x32_bf16(Ah[1][ks], bl, acc1, 0, 0, 0);
      }
      bgc += (labj < 0) ? 1.0f : 0.0f;  // per-lane bg-column count (exact)
#pragma unroll
      for (int tr = 0; tr < 2; ++tr) {
        float e4[4];
#pragma unroll
        for (int v = 0; v < 4; ++v) {  // 5-op epilogue: exp,add,cmp,sel,add
          const float e = __expf(tr ? acc1[v] : acc0[v]);
          e4[v] = e;
          as_[tr][v] += e;
          ps[tr][v] += (labj == labi[tr][v]) ? e : 0.f;
        }
        if (jbase == r0w + tr * 16) {  // wave-uniform diagonal tile
#pragma unroll
          for (int v = 0; v < 4; ++v)
            if (m == q * 4 + v) es_reg[tr] = e4[v];  // exact self term
        }
      }
    }
  }

  // exact self terms to global, once (diag block: cc == rt>>3)
  if (cc == (rt >> 3) && q == (m >> 2)) {
#pragma unroll
    for (int tr = 0; tr < 2; ++tr) eself[r0w + tr * 16 + m] = es_reg[tr];
  }

  // reduce over the 16 m-lanes (disjoint columns of each row)
  float vbg = bgc;
#pragma unroll
  for (int s = 1; s < 16; s <<= 1) vbg += __shfl_xor(vbg, s);
#pragma unroll
  for (int tr = 0; tr < 2; ++tr)
#pragma unroll
    for (int v = 0; v < 4; ++v) {
      float vp = ps[tr][v], va = as_[tr][v];
#pragma unroll
      for (int s = 1; s < 16; s <<= 1) {
        vp += __shfl_xor(vp, s);
        va += __shfl_xor(va, s);
      }
      if (m == 0)  // bg columns each contributed exactly e=1: subtract
        partials[(size_t)cc * N + r0w + tr * 16 + q * 4 + v] =
            make_float2(vp, va - vbg);
    }

  // ---- fused fold: last block of this row-tile reduces its 128 rows -------
  __threadfence();  // release partials/eself
  __syncthreads();
  if (tid == 0) lastflag = (atomicAdd(&cnt[rt], 1) == NCHUNK - 1) ? 1 : 0;
  __syncthreads();
  if (lastflag) {
    __threadfence();  // acquire all 8 chunk-blocks' stores
    float v0 = 0.f, v1 = 0.f;
    if (tid < 128) {
      const int r = rt * 128 + tid;
      float fps = 0.f, fas = 0.f;
#pragma unroll
      for (int c = 0; c < NCHUNK; ++c) {
        const float2 p = partials[(size_t)c * N + r];
        fps += p.x;
        fas += p.y;
      }
      const float es = eself[r];
      const int lab = labels[r];
      fps -= es;  // self always label-matches; exact cancel if no positives
      fas -= es;  // bg columns already removed per-chunk
      const bool valid = (lab >= 0) && (fps > 0.f);
      // |sim|<=10 => max-clamp inactive; all_sum*e^-M in [1,8191] => its
      // clips inactive; pos-clip binding forces loss=10 anyway => clip-free.
      float loss = 10.0f;
      if (fps > 0.f && fas > 0.f) loss = fminf(logf(fas / fps), 10.0f);
      v0 = valid ? loss : 0.f;
      v1 = valid ? 1.f : 0.f;
    }
#pragma unroll
    for (int s = 1; s < 64; s <<= 1) {
      v0 += __shfl_xor(v0, s);
      v1 += __shfl_xor(v1, s);
    }
    if (tid < 128 && l == 0) { red[0][w] = v0; red[1][w] = v1; }
    __syncthreads();
    if (tid == 0) {
      atomicAdd(&accum[0], red[0][0] + red[0][1]);
      atomicAdd(&accum[1], red[1][0] + red[1][1]);
      __threadfence();
      const unsigned old = atomicAdd((unsigned*)&accum[3], 1u);
      if (old == 63u) {  // last row-tile reducer finalizes
        const float ls = atomicAdd(&accum[0], 0.0f);
        const float nv = atomicAdd(&accum[1], 0.0f);
        out[0] = (nv > 0.f) ? ls / nv : 0.0f;  // nv>0 implies nfg>=2
      }
    }
  }
}

extern "C" void kernel_launch(void* const* d_in, const int* in_sizes, int n_in,
                              void* d_out, int out_size, void* d_ws, size_t ws_size,
                              hipStream_t stream) {
  const float* feat = (const float*)d_in[0];
  const int* labels = (const int*)d_in[1];
  float* out = (float*)d_out;
  char* ws = (char*)d_ws;
  u16* fhi = (u16*)ws;                          // 2 MB
  u16* flo = (u16*)(ws + 2097152);              // 2 MB
  float2* partials = (float2*)(ws + 4194304);   // 8*8192*8 = 512 KB
  float* eself = (float*)(ws + 4718592);        // 32 KB
  float* accum = (float*)(ws + 4751360);        // loss-sum, n_valid, -, ctr
  int* cnt = (int*)(ws + 4751616);              // 64 per-row-tile counters

  cpe_prep<<<N / 16, 256, 0, stream>>>(feat, labels, fhi, flo, accum, cnt);
  cpe_main<<<dim3(N / 128, NCHUNK), 256, 0, stream>>>(fhi, flo, labels, partials,
                                                      eself, accum, cnt, out);
}